// Round 1
// baseline (152.961 us; speedup 1.0000x reference)
//
#include <hip/hip_runtime.h>
#include <stdint.h>

#define NROWS 8192
#define DD 128
#define EPS 1e-8f
#define LOG2E 1.4426950408889634f

// main kernel tiling
#define SPLIT 16      // column splits (blocks cooperating per row-strip)
#define RPB 128       // rows per block (4 waves x 2 strips x 16 rows)
#define CPT 16        // cols per tile

typedef __bf16 bf16x8 __attribute__((ext_vector_type(8)));
typedef float f32x4 __attribute__((ext_vector_type(4)));

__device__ __forceinline__ unsigned short f2bf(float f) {
  union { float f; unsigned int u; } v; v.f = f;
  unsigned int u = v.u;
  unsigned int r = (u + 0x7fffu + ((u >> 16) & 1u)) >> 16;
  return (unsigned short)r;
}

// Kernel 1: per-row normalize (store bf16), proxy cosine -> p_i, zero accumulators.
// One wave per row; block = 4 waves.
__global__ __launch_bounds__(256) void norm_kernel(
    const float* __restrict__ x, const float* __restrict__ pr,
    const float* __restrict__ tptr, const float* __restrict__ mptr,
    unsigned short* __restrict__ xn, float* __restrict__ p,
    float* __restrict__ tot, float* __restrict__ msk)
{
  int wave = threadIdx.x >> 6, lane = threadIdx.x & 63;
  int row = blockIdx.x * 4 + wave;
  const float2* xr = (const float2*)(x + (size_t)row * DD);
  const float2* pw = (const float2*)(pr + (size_t)row * DD);
  float2 xv = xr[lane];
  float2 pv = pw[lane];
  float sx = xv.x * xv.x + xv.y * xv.y;
  float sp = pv.x * pv.x + pv.y * pv.y;
  float dp = xv.x * pv.x + xv.y * pv.y;
  #pragma unroll
  for (int m = 1; m < 64; m <<= 1) {
    sx += __shfl_xor(sx, m);
    sp += __shfl_xor(sp, m);
    dp += __shfl_xor(dp, m);
  }
  float inx = 1.f / fmaxf(sqrtf(sx), EPS);
  float inp = 1.f / fmaxf(sqrtf(sp), EPS);
  // store normalized row as bf16 (packed pair per lane)
  unsigned int u0 = f2bf(xv.x * inx);
  unsigned int u1 = f2bf(xv.y * inx);
  ((unsigned int*)(xn + (size_t)row * DD))[lane] = u0 | (u1 << 16);
  if (lane == 0) {
    float T = tptr[0], mg = mptr[0];
    float cosv = dp * inx * inp;
    p[row] = exp2f((cosv - mg) * (LOG2E / T));
    tot[row] = 0.f;
    msk[row] = 0.f;
  }
}

// Kernel 2: fused sim-GEMM + exp + masked/total row-sum accumulation.
// Block = 256 threads = 4 waves; each wave owns 2 strips of 16 rows (RPB=128).
// Grid: (NROWS/RPB, SPLIT); each block walks NROWS/SPLIT columns in 16-col tiles.
__global__ __launch_bounds__(256) void main_kernel(
    const unsigned short* __restrict__ xn_u, const float* __restrict__ negmask,
    const int* __restrict__ labels, const float* __restrict__ tptr,
    const float* __restrict__ mptr, float* __restrict__ tot,
    float* __restrict__ msk)
{
  int wave = threadIdx.x >> 6, lane = threadIdx.x & 63;
  int q = lane >> 4, c = lane & 15;
  int rb0 = blockIdx.x * RPB + wave * 16;  // strip 0 row base
  int rb1 = rb0 + 64;                      // strip 1 row base
  float T = tptr[0], mg = mptr[0];
  float s1 = LOG2E / T;
  float s0 = -mg * s1;

  const bf16x8* xnv = (const bf16x8*)xn_u;  // row = 16 chunks of 8 elems

  // A fragments, held for the whole column loop.
  // A-frag layout: m = lane&15, k = (lane>>4)*8 + j (per 32-wide K step s)
  bf16x8 a0[4], a1[4];
  {
    const bf16x8* b = xnv + (size_t)(rb0 + c) * (DD / 8) + q;
    a0[0] = b[0]; a0[1] = b[4]; a0[2] = b[8]; a0[3] = b[12];
  }
  {
    const bf16x8* b = xnv + (size_t)(rb1 + c) * (DD / 8) + q;
    a1[0] = b[0]; a1[1] = b[4]; a1[2] = b[8]; a1[3] = b[12];
  }

  // Epilogue rows for this lane: row_local = q*4 + k, col = c
  int r0[4], r1[4];
  const float* pm0[4];
  const float* pm1[4];
  #pragma unroll
  for (int k = 0; k < 4; k++) {
    r0[k] = rb0 + q * 4 + k;
    r1[k] = rb1 + q * 4 + k;
    pm0[k] = negmask + (size_t)labels[r0[k]] * NROWS;
    pm1[k] = negmask + (size_t)labels[r1[k]] * NROWS;
  }
  float t0[4] = {0, 0, 0, 0}, m0[4] = {0, 0, 0, 0};
  float t1[4] = {0, 0, 0, 0}, m1[4] = {0, 0, 0, 0};

  int jb = blockIdx.y * (NROWS / SPLIT);
  int je = jb + (NROWS / SPLIT);
  for (int j0 = jb; j0 < je; j0 += CPT) {
    int jg = j0 + c;
    const bf16x8* bb = xnv + (size_t)jg * (DD / 8) + q;
    bf16x8 bf0 = bb[0], bf1 = bb[4], bf2 = bb[8], bf3 = bb[12];

    f32x4 acc0 = {0, 0, 0, 0};
    acc0 = __builtin_amdgcn_mfma_f32_16x16x32_bf16(a0[0], bf0, acc0, 0, 0, 0);
    acc0 = __builtin_amdgcn_mfma_f32_16x16x32_bf16(a0[1], bf1, acc0, 0, 0, 0);
    acc0 = __builtin_amdgcn_mfma_f32_16x16x32_bf16(a0[2], bf2, acc0, 0, 0, 0);
    acc0 = __builtin_amdgcn_mfma_f32_16x16x32_bf16(a0[3], bf3, acc0, 0, 0, 0);
    f32x4 acc1 = {0, 0, 0, 0};
    acc1 = __builtin_amdgcn_mfma_f32_16x16x32_bf16(a1[0], bf0, acc1, 0, 0, 0);
    acc1 = __builtin_amdgcn_mfma_f32_16x16x32_bf16(a1[1], bf1, acc1, 0, 0, 0);
    acc1 = __builtin_amdgcn_mfma_f32_16x16x32_bf16(a1[2], bf2, acc1, 0, 0, 0);
    acc1 = __builtin_amdgcn_mfma_f32_16x16x32_bf16(a1[3], bf3, acc1, 0, 0, 0);

    #pragma unroll
    for (int k = 0; k < 4; k++) {
      float mk = pm0[k][jg];
      float e = __builtin_amdgcn_exp2f(acc0[k] * s1 + s0);
      e = (r0[k] == jg) ? 0.f : e;
      t0[k] += e;
      m0[k] += e * mk;
    }
    #pragma unroll
    for (int k = 0; k < 4; k++) {
      float mk = pm1[k][jg];
      float e = __builtin_amdgcn_exp2f(acc1[k] * s1 + s0);
      e = (r1[k] == jg) ? 0.f : e;
      t1[k] += e;
      m1[k] += e * mk;
    }
  }

  // Reduce across the 16 lanes (c) sharing each q group.
  #pragma unroll
  for (int sh = 1; sh < 16; sh <<= 1) {
    #pragma unroll
    for (int k = 0; k < 4; k++) {
      t0[k] += __shfl_xor(t0[k], sh);
      m0[k] += __shfl_xor(m0[k], sh);
      t1[k] += __shfl_xor(t1[k], sh);
      m1[k] += __shfl_xor(m1[k], sh);
    }
  }
  if (c == 0) {
    #pragma unroll
    for (int k = 0; k < 4; k++) {
      atomicAdd(&tot[r0[k]], t0[k]);
      atomicAdd(&msk[r0[k]], m0[k]);
      atomicAdd(&tot[r1[k]], t1[k]);
      atomicAdd(&msk[r1[k]], m1[k]);
    }
  }
}

// Kernel 3: loss = mean(log(p+tot) - log(p+msk))
__global__ __launch_bounds__(256) void loss_kernel(
    const float* __restrict__ p, const float* __restrict__ tot,
    const float* __restrict__ msk, float* __restrict__ out)
{
  __shared__ float sd[4];
  float s = 0.f;
  for (int r = threadIdx.x; r < NROWS; r += 256) {
    float pi = p[r];
    s += logf(pi + tot[r]) - logf(pi + msk[r]);
  }
  #pragma unroll
  for (int sh = 1; sh < 64; sh <<= 1) s += __shfl_xor(s, sh);
  int wave = threadIdx.x >> 6, lane = threadIdx.x & 63;
  if (lane == 0) sd[wave] = s;
  __syncthreads();
  if (threadIdx.x == 0) out[0] = (sd[0] + sd[1] + sd[2] + sd[3]) / (float)NROWS;
}

extern "C" void kernel_launch(void* const* d_in, const int* in_sizes, int n_in,
                              void* d_out, int out_size, void* d_ws, size_t ws_size,
                              hipStream_t stream) {
  const float* x  = (const float*)d_in[0];   // inst_embed [N,D]
  const float* pr = (const float*)d_in[1];   // proxy [N,D]
  const float* nm = (const float*)d_in[2];   // negative_mask [100,N]
  const int*   lb = (const int*)d_in[3];     // labels [N]
  const float* tp = (const float*)d_in[4];   // temperature
  const float* mp = (const float*)d_in[5];   // margin

  char* ws = (char*)d_ws;
  unsigned short* xn = (unsigned short*)ws;                    // 2 MB bf16
  float* p   = (float*)(ws + (size_t)NROWS * DD * 2);
  float* tot = p + NROWS;
  float* msk = tot + NROWS;
  float* out = (float*)d_out;

  norm_kernel<<<NROWS / 4, 256, 0, stream>>>(x, pr, tp, mp, xn, p, tot, msk);
  main_kernel<<<dim3(NROWS / RPB, SPLIT), 256, 0, stream>>>(xn, nm, lb, tp, mp, tot, msk);
  loss_kernel<<<1, 256, 0, stream>>>(p, tot, msk, out);
}

// Round 2
// 149.119 us; speedup vs baseline: 1.0258x; 1.0258x over previous
//
#include <hip/hip_runtime.h>
#include <stdint.h>

#define NROWS 8192
#define DD 128
#define EPS 1e-8f
#define LOG2E 1.4426950408889634f

// main kernel tiling
#define SPLIT 32      // column splits (blocks cooperating per row-strip)
#define RPB 128       // rows per block (4 waves x 2 strips x 16 rows)
#define CPT 16        // cols per tile

typedef __bf16 bf16x8 __attribute__((ext_vector_type(8)));
typedef float f32x4 __attribute__((ext_vector_type(4)));

__device__ __forceinline__ unsigned int f2bf(float f) {
  union { float f; unsigned int u; } v; v.f = f;
  unsigned int u = v.u;
  return (u + 0x7fffu + ((u >> 16) & 1u)) >> 16;
}
__device__ __forceinline__ float bf2f(unsigned int b) {
  union { unsigned int u; float f; } v; v.u = b << 16;
  return v.f;
}

// Kernel 1: per-row normalize. Writes two bf16 copies of the normalized rows:
//   xnA = bf16(x/||x|| * log2e/T)   (A operand, pre-scaled so e = exp2(acc))
//   xnB = bf16(x/||x||)             (B operand)
// Also: p = exp2(cos(x,proxy)*log2e/T)  [margin cancels in num/den ratio],
// e_self = exp2(sum(xnA_bf16 * xnB_bf16)) (the MFMA diagonal term, subtracted
// later), m_ii = negmask[label_i][i], zero accumulators + out.
__global__ __launch_bounds__(256) void norm_kernel(
    const float* __restrict__ x, const float* __restrict__ pr,
    const float* __restrict__ nm, const int* __restrict__ lb,
    const float* __restrict__ tptr,
    unsigned short* __restrict__ xnA, unsigned short* __restrict__ xnB,
    float* __restrict__ p, float* __restrict__ eself, float* __restrict__ mii,
    float* __restrict__ tot, float* __restrict__ msk, float* __restrict__ out)
{
  int wave = threadIdx.x >> 6, lane = threadIdx.x & 63;
  int row = blockIdx.x * 4 + wave;
  float2 xv = ((const float2*)(x + (size_t)row * DD))[lane];
  float2 pv = ((const float2*)(pr + (size_t)row * DD))[lane];
  float sx = xv.x * xv.x + xv.y * xv.y;
  float sp = pv.x * pv.x + pv.y * pv.y;
  float dp = xv.x * pv.x + xv.y * pv.y;
  #pragma unroll
  for (int m = 1; m < 64; m <<= 1) {
    sx += __shfl_xor(sx, m);
    sp += __shfl_xor(sp, m);
    dp += __shfl_xor(dp, m);
  }
  float inx = 1.f / fmaxf(sqrtf(sx), EPS);
  float inp = 1.f / fmaxf(sqrtf(sp), EPS);
  float s1 = LOG2E / tptr[0];

  unsigned int a0 = f2bf(xv.x * inx * s1), a1 = f2bf(xv.y * inx * s1);
  unsigned int b0 = f2bf(xv.x * inx),      b1 = f2bf(xv.y * inx);
  ((unsigned int*)(xnA + (size_t)row * DD))[lane] = a0 | (a1 << 16);
  ((unsigned int*)(xnB + (size_t)row * DD))[lane] = b0 | (b1 << 16);

  // self-sim with the SAME rounded values the MFMA will see
  float ss = bf2f(a0) * bf2f(b0) + bf2f(a1) * bf2f(b1);
  #pragma unroll
  for (int m = 1; m < 64; m <<= 1) ss += __shfl_xor(ss, m);

  if (lane == 0) {
    p[row] = __builtin_amdgcn_exp2f(dp * inx * inp * s1);
    eself[row] = __builtin_amdgcn_exp2f(ss);
    mii[row] = nm[(size_t)lb[row] * NROWS + row];
    tot[row] = 0.f;
    msk[row] = 0.f;
    if (row == 0) out[0] = 0.f;
  }
}

// Kernel 2: fused sim-GEMM + exp + masked/total row-sum accumulation.
// Block = 256 threads = 4 waves; each wave owns 2 strips of 16 rows (RPB=128).
// Grid: (NROWS/RPB, SPLIT); each block walks NROWS/SPLIT cols in 16-col tiles.
// Software-prefetch next tile's B-frags + mask values into registers.
__global__ __launch_bounds__(256, 4) void main_kernel(
    const unsigned short* __restrict__ xnA_u, const unsigned short* __restrict__ xnB_u,
    const float* __restrict__ negmask, const int* __restrict__ labels,
    float* __restrict__ tot, float* __restrict__ msk)
{
  int wave = threadIdx.x >> 6, lane = threadIdx.x & 63;
  int q = lane >> 4, c = lane & 15;
  int rb0 = blockIdx.x * RPB + wave * 16;  // strip 0 row base
  int rb1 = rb0 + 64;                      // strip 1 row base

  const bf16x8* xnvA = (const bf16x8*)xnA_u;
  const bf16x8* xnvB = (const bf16x8*)xnB_u;

  // A fragments (held in registers for the whole column loop)
  // layout: m = lane&15, k = (lane>>4)*8 + j  per 32-wide K step
  bf16x8 a0[4], a1[4];
  {
    const bf16x8* b = xnvA + (size_t)(rb0 + c) * (DD / 8) + q;
    a0[0] = b[0]; a0[1] = b[4]; a0[2] = b[8]; a0[3] = b[12];
  }
  {
    const bf16x8* b = xnvA + (size_t)(rb1 + c) * (DD / 8) + q;
    a1[0] = b[0]; a1[1] = b[4]; a1[2] = b[8]; a1[3] = b[12];
  }

  // Epilogue rows for this lane: row_local = q*4 + k, col = c
  int r0[4], r1[4];
  unsigned int off0[4], off1[4];   // 32-bit negmask row offsets (base in SGPR)
  #pragma unroll
  for (int k = 0; k < 4; k++) {
    r0[k] = rb0 + q * 4 + k;
    r1[k] = rb1 + q * 4 + k;
    off0[k] = (unsigned int)labels[r0[k]] * (unsigned int)NROWS;
    off1[k] = (unsigned int)labels[r1[k]] * (unsigned int)NROWS;
  }
  float t0[4] = {0, 0, 0, 0}, m0[4] = {0, 0, 0, 0};
  float t1[4] = {0, 0, 0, 0}, m1[4] = {0, 0, 0, 0};

  int jb = blockIdx.y * (NROWS / SPLIT);
  int je = jb + (NROWS / SPLIT);

  // prefetch tile 0
  int jg = jb + c;
  const bf16x8* bp = xnvB + (size_t)jg * (DD / 8) + q;
  bf16x8 nb0 = bp[0], nb1 = bp[4], nb2 = bp[8], nb3 = bp[12];
  float nk0[4], nk1[4];
  #pragma unroll
  for (int k = 0; k < 4; k++) {
    nk0[k] = negmask[off0[k] + jg];
    nk1[k] = negmask[off1[k] + jg];
  }

  for (int j0 = jb; j0 < je; j0 += CPT) {
    bf16x8 b0 = nb0, b1 = nb1, b2 = nb2, b3 = nb3;
    float ck0[4], ck1[4];
    #pragma unroll
    for (int k = 0; k < 4; k++) { ck0[k] = nk0[k]; ck1[k] = nk1[k]; }

    // issue next tile's loads (in flight during MFMA + epilogue)
    int jn = (j0 + CPT < je) ? (j0 + CPT) : jb;
    int jgn = jn + c;
    const bf16x8* np = xnvB + (size_t)jgn * (DD / 8) + q;
    nb0 = np[0]; nb1 = np[4]; nb2 = np[8]; nb3 = np[12];
    #pragma unroll
    for (int k = 0; k < 4; k++) {
      nk0[k] = negmask[off0[k] + jgn];
      nk1[k] = negmask[off1[k] + jgn];
    }

    f32x4 acc0 = {0, 0, 0, 0};
    f32x4 acc1 = {0, 0, 0, 0};
    acc0 = __builtin_amdgcn_mfma_f32_16x16x32_bf16(a0[0], b0, acc0, 0, 0, 0);
    acc1 = __builtin_amdgcn_mfma_f32_16x16x32_bf16(a1[0], b0, acc1, 0, 0, 0);
    acc0 = __builtin_amdgcn_mfma_f32_16x16x32_bf16(a0[1], b1, acc0, 0, 0, 0);
    acc1 = __builtin_amdgcn_mfma_f32_16x16x32_bf16(a1[1], b1, acc1, 0, 0, 0);
    acc0 = __builtin_amdgcn_mfma_f32_16x16x32_bf16(a0[2], b2, acc0, 0, 0, 0);
    acc1 = __builtin_amdgcn_mfma_f32_16x16x32_bf16(a1[2], b2, acc1, 0, 0, 0);
    acc0 = __builtin_amdgcn_mfma_f32_16x16x32_bf16(a0[3], b3, acc0, 0, 0, 0);
    acc1 = __builtin_amdgcn_mfma_f32_16x16x32_bf16(a1[3], b3, acc1, 0, 0, 0);

    // epilogue: 3 VALU ops per element (exp2, add, fma)
    #pragma unroll
    for (int k = 0; k < 4; k++) {
      float e = __builtin_amdgcn_exp2f(acc0[k]);
      t0[k] += e;
      m0[k] = fmaf(e, ck0[k], m0[k]);
    }
    #pragma unroll
    for (int k = 0; k < 4; k++) {
      float e = __builtin_amdgcn_exp2f(acc1[k]);
      t1[k] += e;
      m1[k] = fmaf(e, ck1[k], m1[k]);
    }
  }

  // Reduce across the 16 lanes (c) sharing each q group.
  #pragma unroll
  for (int sh = 1; sh < 16; sh <<= 1) {
    #pragma unroll
    for (int k = 0; k < 4; k++) {
      t0[k] += __shfl_xor(t0[k], sh);
      m0[k] += __shfl_xor(m0[k], sh);
      t1[k] += __shfl_xor(t1[k], sh);
      m1[k] += __shfl_xor(m1[k], sh);
    }
  }
  if (c == 0) {
    #pragma unroll
    for (int k = 0; k < 4; k++) {
      atomicAdd(&tot[r0[k]], t0[k]);
      atomicAdd(&msk[r0[k]], m0[k]);
      atomicAdd(&tot[r1[k]], t1[k]);
      atomicAdd(&msk[r1[k]], m1[k]);
    }
  }
}

// Kernel 3: loss = mean(log(p+tot') - log(p+msk')), diagonal subtracted here.
// 32 blocks x 256 threads, one row per thread, atomicAdd partials into out[0].
__global__ __launch_bounds__(256) void loss_kernel(
    const float* __restrict__ p, const float* __restrict__ tot,
    const float* __restrict__ msk, const float* __restrict__ eself,
    const float* __restrict__ mii, float* __restrict__ out)
{
  __shared__ float sd[4];
  int r = blockIdx.x * 256 + threadIdx.x;
  float pi = p[r];
  float es = eself[r];
  float t = tot[r] - es;                 // remove diagonal from total sum
  float m = msk[r] - es * mii[r];        // remove diagonal from masked sum
  float v = __builtin_amdgcn_logf(pi + t) - __builtin_amdgcn_logf(pi + m);
  float s = v * (1.0f / (LOG2E * (float)NROWS));
  #pragma unroll
  for (int sh = 1; sh < 64; sh <<= 1) s += __shfl_xor(s, sh);
  int wave = threadIdx.x >> 6, lane = threadIdx.x & 63;
  if (lane == 0) sd[wave] = s;
  __syncthreads();
  if (threadIdx.x == 0) atomicAdd(out, sd[0] + sd[1] + sd[2] + sd[3]);
}

extern "C" void kernel_launch(void* const* d_in, const int* in_sizes, int n_in,
                              void* d_out, int out_size, void* d_ws, size_t ws_size,
                              hipStream_t stream) {
  const float* x  = (const float*)d_in[0];   // inst_embed [N,D]
  const float* pr = (const float*)d_in[1];   // proxy [N,D]
  const float* nm = (const float*)d_in[2];   // negative_mask [100,N]
  const int*   lb = (const int*)d_in[3];     // labels [N]
  const float* tp = (const float*)d_in[4];   // temperature
  // margin (d_in[5]) cancels algebraically in numerator/denominator

  char* ws = (char*)d_ws;
  unsigned short* xnA = (unsigned short*)ws;                        // 2 MB
  unsigned short* xnB = xnA + (size_t)NROWS * DD;                   // 2 MB
  float* p     = (float*)(xnB + (size_t)NROWS * DD);
  float* tot   = p + NROWS;
  float* msk   = tot + NROWS;
  float* eself = msk + NROWS;
  float* miiv  = eself + NROWS;
  float* out = (float*)d_out;

  norm_kernel<<<NROWS / 4, 256, 0, stream>>>(x, pr, nm, lb, tp, xnA, xnB, p,
                                             eself, miiv, tot, msk, out);
  main_kernel<<<dim3(NROWS / RPB, SPLIT), 256, 0, stream>>>(xnA, xnB, nm, lb,
                                                            tot, msk);
  loss_kernel<<<NROWS / 256, 256, 0, stream>>>(p, tot, msk, eself, miiv, out);
}

// Round 3
// 103.363 us; speedup vs baseline: 1.4798x; 1.4427x over previous
//
#include <hip/hip_runtime.h>
#include <stdint.h>

#define NROWS 8192
#define DD 128
#define EPS 1e-8f
#define LOG2E 1.4426950408889634f

// main kernel tiling
#define SPLIT 16       // column splits (blocks cooperating per row-strip)
#define RPB 128        // rows per block (4 waves x 2 strips x 16 rows)
#define CPT 32         // cols per LDS tile
#define LDS_COL 272    // bytes per staged col (256 + 16 pad -> 2-way reads)
#define NORM_BLOCKS (NROWS / 4)
#define PACK_BLOCKS 3200   // 100 classes * 128 u64-words / 4 waves

typedef __bf16 bf16x8 __attribute__((ext_vector_type(8)));
typedef float f32x4 __attribute__((ext_vector_type(4)));

__device__ __forceinline__ unsigned int f2bf(float f) {
  union { float f; unsigned int u; } v; v.f = f;
  unsigned int u = v.u;
  return (u + 0x7fffu + ((u >> 16) & 1u)) >> 16;
}
__device__ __forceinline__ float bf2f(unsigned int b) {
  union { unsigned int u; float f; } v; v.u = b << 16;
  return v.f;
}

// Kernel 1 (blocks < NORM_BLOCKS): per-row normalize.
//   xnA = bf16(x/||x|| * log2e/T)  (A operand pre-scaled: e = exp2(acc))
//   xnB = bf16(x/||x||)            (B operand)
//   p = exp2(cos(x,proxy)*log2e/T)  [margin cancels in num/den ratio]
//   e_self = exp2(<xnA_bf16, xnB_bf16>)  (MFMA diagonal, subtracted in loss)
//   mii = negmask[label_i][i]; zero tot/msk/out.
// Kernel 1 (blocks >= NORM_BLOCKS): ballot-pack negmask into u32 bit-words:
//   packed[class*256 + j/32] bit (j&31) = (negmask[class][j] != 0)
__global__ __launch_bounds__(256) void norm_kernel(
    const float* __restrict__ x, const float* __restrict__ pr,
    const float* __restrict__ nm, const int* __restrict__ lb,
    const float* __restrict__ tptr,
    unsigned short* __restrict__ xnA, unsigned short* __restrict__ xnB,
    float* __restrict__ p, float* __restrict__ eself, float* __restrict__ mii,
    float* __restrict__ tot, float* __restrict__ msk,
    unsigned int* __restrict__ packed, float* __restrict__ out)
{
  int wave = threadIdx.x >> 6, lane = threadIdx.x & 63;
  int bx = blockIdx.x;

  if (bx >= NORM_BLOCKS) {
    // ---- mask pack branch ----
    int widx = (bx - NORM_BLOCKS) * 4 + wave;   // 0..12799
    int cls = widx >> 7;                        // 0..99
    int w64 = widx & 127;                       // u64-word within class
    float v = nm[(size_t)cls * NROWS + w64 * 64 + lane];
    unsigned long long b = __ballot(v != 0.0f);
    if (lane == 0) {
      packed[cls * 256 + w64 * 2] = (unsigned int)b;
      packed[cls * 256 + w64 * 2 + 1] = (unsigned int)(b >> 32);
    }
    return;
  }

  int row = bx * 4 + wave;
  float2 xv = ((const float2*)(x + (size_t)row * DD))[lane];
  float2 pv = ((const float2*)(pr + (size_t)row * DD))[lane];
  float sx = xv.x * xv.x + xv.y * xv.y;
  float sp = pv.x * pv.x + pv.y * pv.y;
  float dp = xv.x * pv.x + xv.y * pv.y;
  #pragma unroll
  for (int m = 1; m < 64; m <<= 1) {
    sx += __shfl_xor(sx, m);
    sp += __shfl_xor(sp, m);
    dp += __shfl_xor(dp, m);
  }
  float inx = 1.f / fmaxf(sqrtf(sx), EPS);
  float inp = 1.f / fmaxf(sqrtf(sp), EPS);
  float s1 = LOG2E / tptr[0];

  unsigned int a0 = f2bf(xv.x * inx * s1), a1 = f2bf(xv.y * inx * s1);
  unsigned int b0 = f2bf(xv.x * inx),      b1 = f2bf(xv.y * inx);
  ((unsigned int*)(xnA + (size_t)row * DD))[lane] = a0 | (a1 << 16);
  ((unsigned int*)(xnB + (size_t)row * DD))[lane] = b0 | (b1 << 16);

  // self-sim with the SAME rounded values the MFMA will see
  float ss = bf2f(a0) * bf2f(b0) + bf2f(a1) * bf2f(b1);
  #pragma unroll
  for (int m = 1; m < 64; m <<= 1) ss += __shfl_xor(ss, m);

  if (lane == 0) {
    p[row] = __builtin_amdgcn_exp2f(dp * inx * inp * s1);
    eself[row] = __builtin_amdgcn_exp2f(ss);
    mii[row] = nm[(size_t)lb[row] * NROWS + row];
    tot[row] = 0.f;
    msk[row] = 0.f;
    if (row == 0) out[0] = 0.f;
  }
}

// Kernel 2: fused sim-GEMM + exp + masked/total row-sum accumulation.
// Block = 256 threads = 4 waves; each wave owns 2 strips of 16 rows (RPB=128).
// Grid: (NROWS/RPB, SPLIT). B tiles (CPT=32 cols) are staged through LDS with
// coalesced global loads (2x 1KB per wave) + padded stride; masks are
// bit-packed u32 per 32 cols. Global->reg prefetch one tile ahead.
__global__ __launch_bounds__(256, 4) void main_kernel(
    const unsigned short* __restrict__ xnA_u, const unsigned short* __restrict__ xnB_u,
    const unsigned int* __restrict__ packed, const int* __restrict__ labels,
    float* __restrict__ tot, float* __restrict__ msk)
{
  __shared__ unsigned char lds[CPT * LDS_COL];   // 8704 B
  int tid = threadIdx.x;
  int wave = tid >> 6, lane = tid & 63;
  int q = lane >> 4, c = lane & 15;
  int rb0 = blockIdx.x * RPB + wave * 16;  // strip 0 row base
  int rb1 = rb0 + 64;                      // strip 1 row base

  const bf16x8* xnvA = (const bf16x8*)xnA_u;

  // A fragments (held in registers for the whole column loop)
  // layout: m = lane&15, k = (lane>>4)*8 + j  per 32-wide K step
  bf16x8 a0[4], a1[4];
  {
    const bf16x8* b = xnvA + (size_t)(rb0 + c) * (DD / 8) + q;
    a0[0] = b[0]; a0[1] = b[4]; a0[2] = b[8]; a0[3] = b[12];
  }
  {
    const bf16x8* b = xnvA + (size_t)(rb1 + c) * (DD / 8) + q;
    a1[0] = b[0]; a1[1] = b[4]; a1[2] = b[8]; a1[3] = b[12];
  }

  int jb = blockIdx.y * (NROWS / SPLIT);
  const int NT = (NROWS / SPLIT) / CPT;   // 16 tiles

  // Epilogue rows for this lane: row_local = q*4 + k, col = subtile*16 + c
  int r0[4], r1[4];
  unsigned int offP0[4], offP1[4];        // packed-mask word offsets
  #pragma unroll
  for (int k = 0; k < 4; k++) {
    r0[k] = rb0 + q * 4 + k;
    r1[k] = rb1 + q * 4 + k;
    offP0[k] = (unsigned int)labels[r0[k]] * 256u + (unsigned int)(jb >> 5);
    offP1[k] = (unsigned int)labels[r1[k]] * 256u + (unsigned int)(jb >> 5);
  }
  float t0[4] = {0, 0, 0, 0}, m0[4] = {0, 0, 0, 0};
  float t1[4] = {0, 0, 0, 0}, m1[4] = {0, 0, 0, 0};

  // staging assignment: thread t stages 16B: col = t/16 (+16), chunk = t%16
  int scol = tid >> 4, schunk = tid & 15;
  uint4* ldsw0 = (uint4*)(lds + scol * LDS_COL + schunk * 16);
  uint4* ldsw1 = (uint4*)(lds + (scol + 16) * LDS_COL + schunk * 16);
  const char* gB = (const char*)xnB_u;
  const char* gbase0 = gB + (size_t)(jb + scol) * 256 + schunk * 16;
  const char* gbase1 = gbase0 + 16 * 256;

  // prefetch tile 0
  uint4 g0 = *(const uint4*)(gbase0);
  uint4 g1 = *(const uint4*)(gbase1);
  unsigned int wn0[4], wn1[4];
  #pragma unroll
  for (int k = 0; k < 4; k++) {
    wn0[k] = packed[offP0[k]];
    wn1[k] = packed[offP1[k]];
  }

  for (int t = 0; t < NT; t++) {
    __syncthreads();                 // LDS from tile t-1 fully consumed
    *ldsw0 = g0;                     // reg -> LDS (waits on prefetch loads)
    *ldsw1 = g1;
    unsigned int wc0[4], wc1[4];
    #pragma unroll
    for (int k = 0; k < 4; k++) { wc0[k] = wn0[k]; wc1[k] = wn1[k]; }

    // issue tile t+1 loads (in flight during the whole tile-t compute)
    int tn = (t + 1 < NT) ? t + 1 : 0;
    g0 = *(const uint4*)(gbase0 + (size_t)tn * (CPT * 256));
    g1 = *(const uint4*)(gbase1 + (size_t)tn * (CPT * 256));
    #pragma unroll
    for (int k = 0; k < 4; k++) {
      wn0[k] = packed[offP0[k] + tn];
      wn1[k] = packed[offP1[k] + tn];
    }
    __syncthreads();                 // staged tile visible

    #pragma unroll
    for (int s = 0; s < 2; s++) {
      const bf16x8* bl = (const bf16x8*)(lds + (unsigned)(s * 16 + c) * LDS_COL + q * 16);
      bf16x8 b0 = bl[0], b1 = bl[4], b2 = bl[8], b3 = bl[12];  // chunks q,q+4,q+8,q+12

      f32x4 acc0 = {0, 0, 0, 0};
      f32x4 acc1 = {0, 0, 0, 0};
      acc0 = __builtin_amdgcn_mfma_f32_16x16x32_bf16(a0[0], b0, acc0, 0, 0, 0);
      acc1 = __builtin_amdgcn_mfma_f32_16x16x32_bf16(a1[0], b0, acc1, 0, 0, 0);
      acc0 = __builtin_amdgcn_mfma_f32_16x16x32_bf16(a0[1], b1, acc0, 0, 0, 0);
      acc1 = __builtin_amdgcn_mfma_f32_16x16x32_bf16(a1[1], b1, acc1, 0, 0, 0);
      acc0 = __builtin_amdgcn_mfma_f32_16x16x32_bf16(a0[2], b2, acc0, 0, 0, 0);
      acc1 = __builtin_amdgcn_mfma_f32_16x16x32_bf16(a1[2], b2, acc1, 0, 0, 0);
      acc0 = __builtin_amdgcn_mfma_f32_16x16x32_bf16(a0[3], b3, acc0, 0, 0, 0);
      acc1 = __builtin_amdgcn_mfma_f32_16x16x32_bf16(a1[3], b3, acc1, 0, 0, 0);

      int pos = s * 16 + c;   // bit position in the packed u32 word
      #pragma unroll
      for (int k = 0; k < 4; k++) {
        float e = __builtin_amdgcn_exp2f(acc0[k]);
        t0[k] += e;
        m0[k] = fmaf(e, (float)((wc0[k] >> pos) & 1u), m0[k]);
      }
      #pragma unroll
      for (int k = 0; k < 4; k++) {
        float e = __builtin_amdgcn_exp2f(acc1[k]);
        t1[k] += e;
        m1[k] = fmaf(e, (float)((wc1[k] >> pos) & 1u), m1[k]);
      }
    }
  }

  // Reduce across the 16 lanes (c) sharing each q group.
  #pragma unroll
  for (int sh = 1; sh < 16; sh <<= 1) {
    #pragma unroll
    for (int k = 0; k < 4; k++) {
      t0[k] += __shfl_xor(t0[k], sh);
      m0[k] += __shfl_xor(m0[k], sh);
      t1[k] += __shfl_xor(t1[k], sh);
      m1[k] += __shfl_xor(m1[k], sh);
    }
  }
  if (c == 0) {
    #pragma unroll
    for (int k = 0; k < 4; k++) {
      atomicAdd(&tot[r0[k]], t0[k]);
      atomicAdd(&msk[r0[k]], m0[k]);
      atomicAdd(&tot[r1[k]], t1[k]);
      atomicAdd(&msk[r1[k]], m1[k]);
    }
  }
}

// Kernel 3: loss = mean(log(p+tot') - log(p+msk')), diagonal subtracted here.
__global__ __launch_bounds__(256) void loss_kernel(
    const float* __restrict__ p, const float* __restrict__ tot,
    const float* __restrict__ msk, const float* __restrict__ eself,
    const float* __restrict__ mii, float* __restrict__ out)
{
  __shared__ float sd[4];
  int r = blockIdx.x * 256 + threadIdx.x;
  float pi = p[r];
  float es = eself[r];
  float t = tot[r] - es;                 // remove diagonal from total sum
  float m = msk[r] - es * mii[r];        // remove diagonal from masked sum
  float v = __builtin_amdgcn_logf(pi + t) - __builtin_amdgcn_logf(pi + m);
  float s = v * (1.0f / (LOG2E * (float)NROWS));
  #pragma unroll
  for (int sh = 1; sh < 64; sh <<= 1) s += __shfl_xor(s, sh);
  int wave = threadIdx.x >> 6, lane = threadIdx.x & 63;
  if (lane == 0) sd[wave] = s;
  __syncthreads();
  if (threadIdx.x == 0) atomicAdd(out, sd[0] + sd[1] + sd[2] + sd[3]);
}

extern "C" void kernel_launch(void* const* d_in, const int* in_sizes, int n_in,
                              void* d_out, int out_size, void* d_ws, size_t ws_size,
                              hipStream_t stream) {
  const float* x  = (const float*)d_in[0];   // inst_embed [N,D]
  const float* pr = (const float*)d_in[1];   // proxy [N,D]
  const float* nm = (const float*)d_in[2];   // negative_mask [100,N]
  const int*   lb = (const int*)d_in[3];     // labels [N]
  const float* tp = (const float*)d_in[4];   // temperature
  // margin (d_in[5]) cancels algebraically in numerator/denominator

  char* ws = (char*)d_ws;
  unsigned short* xnA = (unsigned short*)ws;                        // 2 MB
  unsigned short* xnB = xnA + (size_t)NROWS * DD;                   // 2 MB
  float* p     = (float*)(xnB + (size_t)NROWS * DD);
  float* tot   = p + NROWS;
  float* msk   = tot + NROWS;
  float* eself = msk + NROWS;
  float* miiv  = eself + NROWS;
  unsigned int* packed = (unsigned int*)(miiv + NROWS);             // 102.4 KB
  float* out = (float*)d_out;

  norm_kernel<<<NORM_BLOCKS + PACK_BLOCKS, 256, 0, stream>>>(
      x, pr, nm, lb, tp, xnA, xnB, p, eself, miiv, tot, msk, packed, out);
  main_kernel<<<dim3(NROWS / RPB, SPLIT), 256, 0, stream>>>(xnA, xnB, packed,
                                                            lb, tot, msk);
  loss_kernel<<<NROWS / 256, 256, 0, stream>>>(p, tot, msk, eself, miiv, out);
}